// Round 7
// baseline (583.733 us; speedup 1.0000x reference)
//
#include <hip/hip_runtime.h>

// GraphAttentionLayer: B=4, N=4096, F=128, fp32 in/out.
//   w_ij = adj_ij * ( Wh2_j >= -Wh1_i ? P1_i*P2_j : Q1_i*Q2_j )   (softmax scale-invariance
//   + separability of exp(leaky(x+y)) per branch), h = (w @ vp) / rowsum(w), out = leaky(h@Wo^T).
// v8: barrier-free K-loop, SIMPLIFIED pipeline. v6/v7 shared a deep manually-rotated register
// pipeline (8 int4 + 2 Tab via clamped indices); v6 was nondeterministically wrong, v7 killed
// the container twice -> suspect codegen pathology in that structure. v8 keeps the theory
// (no LDS / no barriers in-loop, direct L2 reads of vpT + tables) but uses the v5-verified
// depth-2 adj ping-pong with named registers + wave-uniform conditional prefetch, and plain
// in-body tab/bf loads (compiler hoisting + 2 waves/SIMD TLP cover L2 latency).
// Epilogue: v3-verified per-kh global partials + separate k_out.

constexpr int B = 4, N = 4096, F = 128;
constexpr int BN = B * N;
constexpr int BK = 64;
constexpr int NIT = N / BK;   // 64 iterations over full j-range
#define ALPHA 0.1f

using float4v = __attribute__((ext_vector_type(4))) float;
using short8 = __attribute__((ext_vector_type(8))) short;

__device__ __forceinline__ float leaky(float x) { return x >= 0.f ? x : ALPHA * x; }
__device__ __forceinline__ unsigned short f2bf(float x) {  // RNE float->bf16
    unsigned u = __float_as_uint(x);
    u = (u + 0x7FFFu + ((u >> 16) & 1u)) >> 16;
    return (unsigned short)u;
}
// pack two floats -> two RNE bf16 in one dword: {bf(hi)[31:16], bf(lo)[15:0]}
__device__ __forceinline__ unsigned pack_bf2(float lo, float hi) {
    unsigned a = __float_as_uint(lo), b2 = __float_as_uint(hi);
    a = a + 0x7FFFu + ((a >> 16) & 1u);
    b2 = b2 + 0x7FFFu + ((b2 >> 16) & 1u);
    return __builtin_amdgcn_perm(b2, a, 0x07060302u);  // bytes: b2[3],b2[2],a[3],a[2]
}

// ---------------- K0: c1, c2, d1, d2 ----------------
__global__ void k_prep(const float* __restrict__ Wq_w, const float* __restrict__ Wq_b,
                       const float* __restrict__ Wk_w, const float* __restrict__ Wk_b,
                       const float* __restrict__ a, float* __restrict__ c1,
                       float* __restrict__ c2, float* __restrict__ d12) {
    __shared__ float as[2 * F];
    __shared__ float red[2 * F];
    int t = threadIdx.x;  // 256
    as[t] = a[t];
    __syncthreads();
    int f = t & 127;
    const float* W = (t < F) ? Wq_w : Wk_w;
    const float* ao = (t < F) ? as : as + F;
    float s = 0.f;
#pragma unroll 8
    for (int o = 0; o < F; o++) s = fmaf(W[o * F + f], ao[o], s);
    if (t < F) c1[f] = s; else c2[f] = s;
    red[t] = (t < F) ? Wq_b[f] * as[f] : Wk_b[f] * as[F + f];
    __syncthreads();
    for (int st = 64; st > 0; st >>= 1) {
        if (f < st) red[t] += red[t + st];
        __syncthreads();
    }
    if (t == 0) d12[0] = red[0];
    if (t == F) d12[1] = red[F];
}

// ---------------- K1: Wh1, Wh2 ----------------
__global__ void k_wh(const float* __restrict__ q, const float* __restrict__ k,
                     const float* __restrict__ c1, const float* __restrict__ c2,
                     const float* __restrict__ d12,
                     float* __restrict__ Wh1, float* __restrict__ Wh2) {
    __shared__ float c1s[F], c2s[F];
    int t = threadIdx.x;
    if (t < F) c1s[t] = c1[t]; else c2s[t - F] = c2[t - F];
    __syncthreads();
    int row = blockIdx.x * 8 + (t >> 5);
    int lane = t & 31;
    float4 q4 = reinterpret_cast<const float4*>(q)[row * 32 + lane];
    float4 k4 = reinterpret_cast<const float4*>(k)[row * 32 + lane];
    float s1 = q4.x * c1s[lane * 4 + 0] + q4.y * c1s[lane * 4 + 1] +
               q4.z * c1s[lane * 4 + 2] + q4.w * c1s[lane * 4 + 3];
    float s2 = k4.x * c2s[lane * 4 + 0] + k4.y * c2s[lane * 4 + 1] +
               k4.z * c2s[lane * 4 + 2] + k4.w * c2s[lane * 4 + 3];
    for (int m = 16; m > 0; m >>= 1) { s1 += __shfl_xor(s1, m); s2 += __shfl_xor(s2, m); }
    if (lane == 0) { Wh1[row] = s1 + d12[0]; Wh2[row] = s2 + d12[1]; }
}

// ---------------- K1b: per-batch max of Wh2 ----------------
__global__ void k_max2(const float* __restrict__ Wh2, float* __restrict__ M2) {
    int b = blockIdx.x, t = threadIdx.x;
    float m = -1e30f;
    for (int i = t; i < N; i += 256) m = fmaxf(m, Wh2[b * N + i]);
    __shared__ float red[256];
    red[t] = m;
    __syncthreads();
    for (int s = 128; s > 0; s >>= 1) { if (t < s) red[t] = fmaxf(red[t], red[t + s]); __syncthreads(); }
    if (t == 0) M2[b] = red[0];
}

// ---------------- K1c: exp tables ----------------
__global__ void k_tab(const float* __restrict__ Wh1, const float* __restrict__ Wh2,
                      const float* __restrict__ M2,
                      float* __restrict__ P1, float* __restrict__ Q1,
                      float* __restrict__ P2, float* __restrict__ Q2) {
    int i = blockIdx.x * 256 + threadIdx.x;
    int b = i >> 12;  // N = 4096
    float w1 = Wh1[i], w2 = Wh2[i];
    float mi = leaky(w1 + M2[b]);  // per-row shift (cancels in h; range only)
    P1[i] = __expf(w1 - mi);
    Q1[i] = __expf(ALPHA * w1 - mi);
    P2[i] = __expf(w2);
    Q2[i] = __expf(ALPHA * w2);
}

// ---------------- K2: vpT = bf16( (v @ Wv^T + bv)^T ), layout [B][F][N] ----------------
__global__ __launch_bounds__(256) void k_vp(const float* __restrict__ v,
                                            const float* __restrict__ Wv_w,
                                            const float* __restrict__ Wv_b,
                                            unsigned short* __restrict__ vpT) {
    __shared__ float vs[32][F];            // 16 KB
    __shared__ float Ws[F][129];           // 66 KB, pad -> conflict-free column reads
    __shared__ unsigned short ts[F][40];   // 10 KB transpose tile (pad 8)
    int t = threadIdx.x;
    int row0g = blockIdx.x * 32;           // flat row in [0, BN)
    int b = row0g >> 12;
    int row0 = row0g & (N - 1);
    {
        const float4* src = reinterpret_cast<const float4*>(v + row0g * F);
        float4* dst = reinterpret_cast<float4*>(&vs[0][0]);
#pragma unroll
        for (int u = 0; u < 4; u++) dst[u * 256 + t] = src[u * 256 + t];
    }
    {
        const float4* src = reinterpret_cast<const float4*>(Wv_w);
#pragma unroll
        for (int u = 0; u < 16; u++) {
            int unit = u * 256 + t;
            int r = unit >> 5, s = unit & 31;
            float4 val = src[unit];
            Ws[r][s * 4 + 0] = val.x; Ws[r][s * 4 + 1] = val.y;
            Ws[r][s * 4 + 2] = val.z; Ws[r][s * 4 + 3] = val.w;
        }
    }
    int f = t & 127, g = t >> 7;
    float bias = Wv_b[f];
    __syncthreads();
    float acc[16];
#pragma unroll
    for (int r = 0; r < 16; r++) acc[r] = bias;
    for (int kk = 0; kk < F; kk++) {
        float wk = Ws[f][kk];
#pragma unroll
        for (int r = 0; r < 16; r++) acc[r] = fmaf(vs[g * 16 + r][kk], wk, acc[r]);
    }
#pragma unroll
    for (int r = 0; r < 16; r++) ts[f][g * 16 + r] = f2bf(acc[r]);
    __syncthreads();
    int fr = t >> 1, hseg = t & 1;
    uint4 d0 = *reinterpret_cast<uint4*>(&ts[fr][hseg * 16]);
    uint4 d1 = *reinterpret_cast<uint4*>(&ts[fr][hseg * 16 + 8]);
    unsigned short* dst = vpT + ((size_t)(b * F + fr) * N + row0 + hseg * 16);
    *reinterpret_cast<uint4*>(dst) = d0;
    *reinterpret_cast<uint4*>(dst + 8) = d1;
}

// ---------------- K3: barrier-free MFMA attention, per-kh partial stores ----------------
__global__ __launch_bounds__(256, 2) void k_attn(
    const unsigned short* __restrict__ vpT, const int* __restrict__ adj,
    const float* __restrict__ Wh1, const float* __restrict__ P1, const float* __restrict__ Q1,
    const float* __restrict__ P2, const float* __restrict__ Q2, const float* __restrict__ Wh2,
    float* __restrict__ h_part, float* __restrict__ den_part) {
    int t = threadIdx.x;             // 256
    int idx = blockIdx.x;            // 512 = B * 128 tiles
    int tile = idx & 127;
    int b = idx >> 7;
    int i0 = tile * 32;
    int widx = t >> 6, lane = t & 63, m = lane & 15, q = lane >> 4;
    int rt = widx >> 1;              // row-tile 0..1
    int kh = widx & 1;               // j-half 0..1
    int r0 = i0 + rt * 16;           // wave's 16 rows

    int gi0 = b * N + r0 + m;        // this lane's row
    float p1a = P1[gi0], q1a = Q1[gi0], t1a = -Wh1[gi0];

    // per-lane base pointers (j-offset kh*32 + q*8 folded in)
    int jo = kh * 32 + q * 8;
    const unsigned short* bfb = vpT + ((size_t)(b * F + m)) * N + jo;  // + nt*16*N + it*BK
    const int* adjb = adj + (size_t)gi0 * N + jo;                      // + it*BK
    const float* W2b = Wh2 + (size_t)b * N + jo;
    const float* P2b = P2 + (size_t)b * N + jo;
    const float* Q2b = Q2 + (size_t)b * N + jo;

    float4v acc0[8];
#pragma unroll
    for (int nt = 0; nt < 8; nt++) acc0[nt] = (float4v){0.f, 0.f, 0.f, 0.f};
    float den0 = 0.f;

    // one K-step: plain loads at body top (L2-hot), masked w-gen, 8 MFMAs
    auto body = [&](int it, const int4& a0, const int4& a1) {
        const float* w = W2b + it * BK;
        float4 x2a = *reinterpret_cast<const float4*>(w);
        float4 x2b = *reinterpret_cast<const float4*>(w + 4);
        const float* p = P2b + it * BK;
        float4 p2a = *reinterpret_cast<const float4*>(p);
        float4 p2b = *reinterpret_cast<const float4*>(p + 4);
        const float* qq = Q2b + it * BK;
        float4 q2a = *reinterpret_cast<const float4*>(qq);
        float4 q2b = *reinterpret_cast<const float4*>(qq + 4);
        const unsigned short* vr = bfb + it * BK;
        short8 bf0 = *reinterpret_cast<const short8*>(vr);
        short8 bf1 = *reinterpret_cast<const short8*>(vr + (size_t)1 * 16 * N);
        short8 bf2 = *reinterpret_cast<const short8*>(vr + (size_t)2 * 16 * N);
        short8 bf3 = *reinterpret_cast<const short8*>(vr + (size_t)3 * 16 * N);
        short8 bf4 = *reinterpret_cast<const short8*>(vr + (size_t)4 * 16 * N);
        short8 bf5 = *reinterpret_cast<const short8*>(vr + (size_t)5 * 16 * N);
        short8 bf6 = *reinterpret_cast<const short8*>(vr + (size_t)6 * 16 * N);
        short8 bf7 = *reinterpret_cast<const short8*>(vr + (size_t)7 * 16 * N);

        float w0 = a0.x ? ((x2a.x >= t1a) ? p1a * p2a.x : q1a * q2a.x) : 0.f;
        float w1 = a0.y ? ((x2a.y >= t1a) ? p1a * p2a.y : q1a * q2a.y) : 0.f;
        float w2 = a0.z ? ((x2a.z >= t1a) ? p1a * p2a.z : q1a * q2a.z) : 0.f;
        float w3 = a0.w ? ((x2a.w >= t1a) ? p1a * p2a.w : q1a * q2a.w) : 0.f;
        float w4 = a1.x ? ((x2b.x >= t1a) ? p1a * p2b.x : q1a * q2b.x) : 0.f;
        float w5 = a1.y ? ((x2b.y >= t1a) ? p1a * p2b.y : q1a * q2b.y) : 0.f;
        float w6 = a1.z ? ((x2b.z >= t1a) ? p1a * p2b.z : q1a * q2b.z) : 0.f;
        float w7 = a1.w ? ((x2b.w >= t1a) ? p1a * p2b.w : q1a * q2b.w) : 0.f;
        den0 += ((w0 + w1) + (w2 + w3)) + ((w4 + w5) + (w6 + w7));
        union { short8 s; uint4 u; } af;
        af.u.x = pack_bf2(w0, w1); af.u.y = pack_bf2(w2, w3);
        af.u.z = pack_bf2(w4, w5); af.u.w = pack_bf2(w6, w7);

        acc0[0] = __builtin_amdgcn_mfma_f32_16x16x32_bf16(af.s, bf0, acc0[0], 0, 0, 0);
        acc0[1] = __builtin_amdgcn_mfma_f32_16x16x32_bf16(af.s, bf1, acc0[1], 0, 0, 0);
        acc0[2] = __builtin_amdgcn_mfma_f32_16x16x32_bf16(af.s, bf2, acc0[2], 0, 0, 0);
        acc0[3] = __builtin_amdgcn_mfma_f32_16x16x32_bf16(af.s, bf3, acc0[3], 0, 0, 0);
        acc0[4] = __builtin_amdgcn_mfma_f32_16x16x32_bf16(af.s, bf4, acc0[4], 0, 0, 0);
        acc0[5] = __builtin_amdgcn_mfma_f32_16x16x32_bf16(af.s, bf5, acc0[5], 0, 0, 0);
        acc0[6] = __builtin_amdgcn_mfma_f32_16x16x32_bf16(af.s, bf6, acc0[6], 0, 0, 0);
        acc0[7] = __builtin_amdgcn_mfma_f32_16x16x32_bf16(af.s, bf7, acc0[7], 0, 0, 0);
    };

    // adj ping-pong, depth 2, named registers, wave-uniform conditional prefetch
    int4 aA0, aA1, aB0, aB1;
    {
        const int* p0 = adjb;
        aA0 = *reinterpret_cast<const int4*>(p0);
        aA1 = *reinterpret_cast<const int4*>(p0 + 4);
        const int* p1 = adjb + BK;
        aB0 = *reinterpret_cast<const int4*>(p1);
        aB1 = *reinterpret_cast<const int4*>(p1 + 4);
    }
#pragma unroll 1
    for (int ith = 0; ith < NIT / 2; ith++) {
        int it = ith * 2;
        body(it, aA0, aA1);
        if (it + 2 < NIT) {
            const int* p = adjb + (size_t)(it + 2) * BK;
            aA0 = *reinterpret_cast<const int4*>(p);
            aA1 = *reinterpret_cast<const int4*>(p + 4);
        }
        body(it + 1, aB0, aB1);
        if (it + 3 < NIT) {
            const int* p = adjb + (size_t)(it + 3) * BK;
            aB0 = *reinterpret_cast<const int4*>(p);
            aB1 = *reinterpret_cast<const int4*>(p + 4);
        }
    }

    // ---- epilogue (v3-verified pattern): per-kh partials, plain global stores ----
    den0 += __shfl_xor(den0, 16);
    den0 += __shfl_xor(den0, 32);
    float* dp = den_part + (size_t)kh * BN;
    if (lane < 16) dp[gi0] = den0;   // lanes 0..15 hold rows r0..r0+15's half-den
    float* hp = h_part + (size_t)kh * BN * F;
    int orow0 = b * N + i0 + rt * 16 + q * 4;  // C/D: row = q*4+reg (within 16-tile), col = nt*16+m
#pragma unroll
    for (int nt = 0; nt < 8; nt++)
#pragma unroll
        for (int r = 0; r < 4; r++)
            hp[(size_t)(orow0 + r) * F + nt * 16 + m] = acc0[nt][r];
}

// ---------------- K4: out = leaky( ((h0+h1)/(d0+d1)) @ Wo^T )  (v3-verified) ----------------
__global__ __launch_bounds__(256) void k_out(const float* __restrict__ h_part,
                                             const float* __restrict__ den_part,
                                             const float* __restrict__ Wo_w,
                                             float* __restrict__ out) {
    __shared__ float hs[32][F];    // 16 KB
    __shared__ float Ws[F][129];   // 66 KB
    int t = threadIdx.x;
    int row0 = blockIdx.x * 32;    // flat row in [0, BN)
    {
        const float4* src = reinterpret_cast<const float4*>(Wo_w);
#pragma unroll
        for (int u = 0; u < 16; u++) {
            int unit = u * 256 + t;
            int r = unit >> 5, s = unit & 31;
            float4 val = src[unit];
            Ws[r][s * 4 + 0] = val.x; Ws[r][s * 4 + 1] = val.y;
            Ws[r][s * 4 + 2] = val.z; Ws[r][s * 4 + 3] = val.w;
        }
    }
#pragma unroll
    for (int u = 0; u < 4; u++) {
        int unit = u * 256 + t;
        int r = unit >> 5, s = unit & 31;
        size_t off = (size_t)(row0 + r) * F + s * 4;
        float4 h0 = *reinterpret_cast<const float4*>(h_part + off);
        float4 h1 = *reinterpret_cast<const float4*>(h_part + (size_t)BN * F + off);
        float dsum = den_part[row0 + r] + den_part[BN + row0 + r];
        float inv = 1.f / dsum;
        hs[r][s * 4 + 0] = (h0.x + h1.x) * inv;
        hs[r][s * 4 + 1] = (h0.y + h1.y) * inv;
        hs[r][s * 4 + 2] = (h0.z + h1.z) * inv;
        hs[r][s * 4 + 3] = (h0.w + h1.w) * inv;
    }
    __syncthreads();
    int f = t & 127, g = t >> 7;
    float acc[16];
#pragma unroll
    for (int r = 0; r < 16; r++) acc[r] = 0.f;
    for (int kk = 0; kk < F; kk++) {
        float wk = Ws[f][kk];
#pragma unroll
        for (int r = 0; r < 16; r++) acc[r] = fmaf(hs[g * 16 + r][kk], wk, acc[r]);
    }
#pragma unroll
    for (int r = 0; r < 16; r++) out[(size_t)(row0 + g * 16 + r) * F + f] = leaky(acc[r]);
}

extern "C" void kernel_launch(void* const* d_in, const int* in_sizes, int n_in,
                              void* d_out, int out_size, void* d_ws, size_t ws_size,
                              hipStream_t stream) {
    const float* q    = (const float*)d_in[0];
    const float* k    = (const float*)d_in[1];
    const float* v    = (const float*)d_in[2];
    const int*   adj  = (const int*)d_in[3];
    const float* Wq_w = (const float*)d_in[4];
    const float* Wq_b = (const float*)d_in[5];
    const float* Wk_w = (const float*)d_in[6];
    const float* Wk_b = (const float*)d_in[7];
    const float* Wv_w = (const float*)d_in[8];
    const float* Wv_b = (const float*)d_in[9];
    const float* a    = (const float*)d_in[10];
    const float* Wo_w = (const float*)d_in[11];
    float* out = (float*)d_out;
    float* ws = (float*)d_ws;

    unsigned short* vpT = (unsigned short*)ws;        // BN*F bf16 = BN*F/2 floats
    float* h_part   = ws + BN * F / 2;                // 2*BN*F
    float* den_part = h_part + (size_t)2 * BN * F;    // 2*BN
    float* Wh1 = den_part + 2 * BN;
    float* Wh2 = Wh1 + BN;
    float* P1  = Wh2 + BN;
    float* Q1  = P1 + BN;
    float* P2  = Q1 + BN;
    float* Q2  = P2 + BN;
    float* c1  = Q2 + BN;                             // F
    float* c2  = c1 + F;                              // F
    float* d12 = c2 + F;                              // 2
    float* M2  = d12 + 2;                             // B

    k_prep<<<1, 256, 0, stream>>>(Wq_w, Wq_b, Wk_w, Wk_b, a, c1, c2, d12);
    k_wh<<<BN / 8, 256, 0, stream>>>(q, k, c1, c2, d12, Wh1, Wh2);
    k_max2<<<B, 256, 0, stream>>>(Wh2, M2);
    k_tab<<<BN / 256, 256, 0, stream>>>(Wh1, Wh2, M2, P1, Q1, P2, Q2);
    k_vp<<<BN / 32, 256, 0, stream>>>(v, Wv_w, Wv_b, vpT);
    k_attn<<<B * 128, 256, 0, stream>>>(vpT, adj, Wh1, P1, Q1, P2, Q2, Wh2,
                                        h_part, den_part);
    k_out<<<BN / 32, 256, 0, stream>>>(h_part, den_part, Wo_w, out);
}

// Round 8
// 570.381 us; speedup vs baseline: 1.0234x; 1.0234x over previous
//
#include <hip/hip_runtime.h>

// GraphAttentionLayer: B=4, N=4096, F=128, fp32 in/out.
//   w_ij = adj_ij * ( Wh2_j >= -Wh1_i ? P1_i*P2_j : Q1_i*Q2_j )   (softmax scale-invariance
//   + separability of exp(leaky(x+y)) per branch), h = (w @ vp) / rowsum(w), out = leaky(h@Wo^T).
// v9: v8's verified barrier-free K-loop + SPLITS=2 j-split to double block supply.
// v4/v5/v8 were all latency-bound at ~200us with <=2 waves/SIMD (grid 512 = 2 blocks/CU was
// the occupancy cap; VGPR=72, LDS=0 allow ~7). Grid 1024 -> 4 blocks/CU = 16 waves/CU; the
// K-loop body/pipeline is byte-identical to v8 (only j-base offsets, NIT=32, partial idx).
// Partials 2 -> 4 (split x kh), combined by v3-verified 4-partial k_out (+~3us round-trip).

constexpr int B = 4, N = 4096, F = 128;
constexpr int BN = B * N;
constexpr int BK = 64;
constexpr int SPLITS = 2;
constexpr int JC = N / SPLITS;    // 2048 j per block
constexpr int NIT = JC / BK;      // 32 iterations
#define ALPHA 0.1f

using float4v = __attribute__((ext_vector_type(4))) float;
using short8 = __attribute__((ext_vector_type(8))) short;

__device__ __forceinline__ float leaky(float x) { return x >= 0.f ? x : ALPHA * x; }
__device__ __forceinline__ unsigned short f2bf(float x) {  // RNE float->bf16
    unsigned u = __float_as_uint(x);
    u = (u + 0x7FFFu + ((u >> 16) & 1u)) >> 16;
    return (unsigned short)u;
}
// pack two floats -> two RNE bf16 in one dword: {bf(hi)[31:16], bf(lo)[15:0]}
__device__ __forceinline__ unsigned pack_bf2(float lo, float hi) {
    unsigned a = __float_as_uint(lo), b2 = __float_as_uint(hi);
    a = a + 0x7FFFu + ((a >> 16) & 1u);
    b2 = b2 + 0x7FFFu + ((b2 >> 16) & 1u);
    return __builtin_amdgcn_perm(b2, a, 0x07060302u);  // bytes: b2[3],b2[2],a[3],a[2]
}

// ---------------- K0: c1, c2, d1, d2 ----------------
__global__ void k_prep(const float* __restrict__ Wq_w, const float* __restrict__ Wq_b,
                       const float* __restrict__ Wk_w, const float* __restrict__ Wk_b,
                       const float* __restrict__ a, float* __restrict__ c1,
                       float* __restrict__ c2, float* __restrict__ d12) {
    __shared__ float as[2 * F];
    __shared__ float red[2 * F];
    int t = threadIdx.x;  // 256
    as[t] = a[t];
    __syncthreads();
    int f = t & 127;
    const float* W = (t < F) ? Wq_w : Wk_w;
    const float* ao = (t < F) ? as : as + F;
    float s = 0.f;
#pragma unroll 8
    for (int o = 0; o < F; o++) s = fmaf(W[o * F + f], ao[o], s);
    if (t < F) c1[f] = s; else c2[f] = s;
    red[t] = (t < F) ? Wq_b[f] * as[f] : Wk_b[f] * as[F + f];
    __syncthreads();
    for (int st = 64; st > 0; st >>= 1) {
        if (f < st) red[t] += red[t + st];
        __syncthreads();
    }
    if (t == 0) d12[0] = red[0];
    if (t == F) d12[1] = red[F];
}

// ---------------- K1: Wh1, Wh2 ----------------
__global__ void k_wh(const float* __restrict__ q, const float* __restrict__ k,
                     const float* __restrict__ c1, const float* __restrict__ c2,
                     const float* __restrict__ d12,
                     float* __restrict__ Wh1, float* __restrict__ Wh2) {
    __shared__ float c1s[F], c2s[F];
    int t = threadIdx.x;
    if (t < F) c1s[t] = c1[t]; else c2s[t - F] = c2[t - F];
    __syncthreads();
    int row = blockIdx.x * 8 + (t >> 5);
    int lane = t & 31;
    float4 q4 = reinterpret_cast<const float4*>(q)[row * 32 + lane];
    float4 k4 = reinterpret_cast<const float4*>(k)[row * 32 + lane];
    float s1 = q4.x * c1s[lane * 4 + 0] + q4.y * c1s[lane * 4 + 1] +
               q4.z * c1s[lane * 4 + 2] + q4.w * c1s[lane * 4 + 3];
    float s2 = k4.x * c2s[lane * 4 + 0] + k4.y * c2s[lane * 4 + 1] +
               k4.z * c2s[lane * 4 + 2] + k4.w * c2s[lane * 4 + 3];
    for (int m = 16; m > 0; m >>= 1) { s1 += __shfl_xor(s1, m); s2 += __shfl_xor(s2, m); }
    if (lane == 0) { Wh1[row] = s1 + d12[0]; Wh2[row] = s2 + d12[1]; }
}

// ---------------- K1b: per-batch max of Wh2 ----------------
__global__ void k_max2(const float* __restrict__ Wh2, float* __restrict__ M2) {
    int b = blockIdx.x, t = threadIdx.x;
    float m = -1e30f;
    for (int i = t; i < N; i += 256) m = fmaxf(m, Wh2[b * N + i]);
    __shared__ float red[256];
    red[t] = m;
    __syncthreads();
    for (int s = 128; s > 0; s >>= 1) { if (t < s) red[t] = fmaxf(red[t], red[t + s]); __syncthreads(); }
    if (t == 0) M2[b] = red[0];
}

// ---------------- K1c: exp tables ----------------
__global__ void k_tab(const float* __restrict__ Wh1, const float* __restrict__ Wh2,
                      const float* __restrict__ M2,
                      float* __restrict__ P1, float* __restrict__ Q1,
                      float* __restrict__ P2, float* __restrict__ Q2) {
    int i = blockIdx.x * 256 + threadIdx.x;
    int b = i >> 12;  // N = 4096
    float w1 = Wh1[i], w2 = Wh2[i];
    float mi = leaky(w1 + M2[b]);  // per-row shift (cancels in h; range only)
    P1[i] = __expf(w1 - mi);
    Q1[i] = __expf(ALPHA * w1 - mi);
    P2[i] = __expf(w2);
    Q2[i] = __expf(ALPHA * w2);
}

// ---------------- K2: vpT = bf16( (v @ Wv^T + bv)^T ), layout [B][F][N] ----------------
__global__ __launch_bounds__(256) void k_vp(const float* __restrict__ v,
                                            const float* __restrict__ Wv_w,
                                            const float* __restrict__ Wv_b,
                                            unsigned short* __restrict__ vpT) {
    __shared__ float vs[32][F];            // 16 KB
    __shared__ float Ws[F][129];           // 66 KB, pad -> conflict-free column reads
    __shared__ unsigned short ts[F][40];   // 10 KB transpose tile (pad 8)
    int t = threadIdx.x;
    int row0g = blockIdx.x * 32;           // flat row in [0, BN)
    int b = row0g >> 12;
    int row0 = row0g & (N - 1);
    {
        const float4* src = reinterpret_cast<const float4*>(v + row0g * F);
        float4* dst = reinterpret_cast<float4*>(&vs[0][0]);
#pragma unroll
        for (int u = 0; u < 4; u++) dst[u * 256 + t] = src[u * 256 + t];
    }
    {
        const float4* src = reinterpret_cast<const float4*>(Wv_w);
#pragma unroll
        for (int u = 0; u < 16; u++) {
            int unit = u * 256 + t;
            int r = unit >> 5, s = unit & 31;
            float4 val = src[unit];
            Ws[r][s * 4 + 0] = val.x; Ws[r][s * 4 + 1] = val.y;
            Ws[r][s * 4 + 2] = val.z; Ws[r][s * 4 + 3] = val.w;
        }
    }
    int f = t & 127, g = t >> 7;
    float bias = Wv_b[f];
    __syncthreads();
    float acc[16];
#pragma unroll
    for (int r = 0; r < 16; r++) acc[r] = bias;
    for (int kk = 0; kk < F; kk++) {
        float wk = Ws[f][kk];
#pragma unroll
        for (int r = 0; r < 16; r++) acc[r] = fmaf(vs[g * 16 + r][kk], wk, acc[r]);
    }
#pragma unroll
    for (int r = 0; r < 16; r++) ts[f][g * 16 + r] = f2bf(acc[r]);
    __syncthreads();
    int fr = t >> 1, hseg = t & 1;
    uint4 d0 = *reinterpret_cast<uint4*>(&ts[fr][hseg * 16]);
    uint4 d1 = *reinterpret_cast<uint4*>(&ts[fr][hseg * 16 + 8]);
    unsigned short* dst = vpT + ((size_t)(b * F + fr) * N + row0 + hseg * 16);
    *reinterpret_cast<uint4*>(dst) = d0;
    *reinterpret_cast<uint4*>(dst + 8) = d1;
}

// ---------------- K3: barrier-free MFMA attention, 4-way (split x kh) partial stores ----------------
__global__ __launch_bounds__(256, 2) void k_attn(
    const unsigned short* __restrict__ vpT, const int* __restrict__ adj,
    const float* __restrict__ Wh1, const float* __restrict__ P1, const float* __restrict__ Q1,
    const float* __restrict__ P2, const float* __restrict__ Q2, const float* __restrict__ Wh2,
    float* __restrict__ h_part, float* __restrict__ den_part) {
    int t = threadIdx.x;             // 256
    int idx = blockIdx.x;            // 1024 = B * 128 tiles * SPLITS
    int split = idx & (SPLITS - 1);
    int tile = (idx / SPLITS) & 127;
    int b = idx / (SPLITS * 128);
    int i0 = tile * 32;
    int jb0 = split * JC;
    int widx = t >> 6, lane = t & 63, m = lane & 15, q = lane >> 4;
    int rt = widx >> 1;              // row-tile 0..1
    int kh = widx & 1;               // j-half 0..1
    int r0 = i0 + rt * 16;           // wave's 16 rows

    int gi0 = b * N + r0 + m;        // this lane's row
    float p1a = P1[gi0], q1a = Q1[gi0], t1a = -Wh1[gi0];

    // per-lane base pointers (j-offset jb0 + kh*32 + q*8 folded in)
    int jo = jb0 + kh * 32 + q * 8;
    const unsigned short* bfb = vpT + ((size_t)(b * F + m)) * N + jo;  // + nt*16*N + it*BK
    const int* adjb = adj + (size_t)gi0 * N + jo;                      // + it*BK
    const float* W2b = Wh2 + (size_t)b * N + jo;
    const float* P2b = P2 + (size_t)b * N + jo;
    const float* Q2b = Q2 + (size_t)b * N + jo;

    float4v acc0[8];
#pragma unroll
    for (int nt = 0; nt < 8; nt++) acc0[nt] = (float4v){0.f, 0.f, 0.f, 0.f};
    float den0 = 0.f;

    // one K-step: plain loads at body top (L2-hot), masked w-gen, 8 MFMAs
    auto body = [&](int it, const int4& a0, const int4& a1) {
        const float* w = W2b + it * BK;
        float4 x2a = *reinterpret_cast<const float4*>(w);
        float4 x2b = *reinterpret_cast<const float4*>(w + 4);
        const float* p = P2b + it * BK;
        float4 p2a = *reinterpret_cast<const float4*>(p);
        float4 p2b = *reinterpret_cast<const float4*>(p + 4);
        const float* qq = Q2b + it * BK;
        float4 q2a = *reinterpret_cast<const float4*>(qq);
        float4 q2b = *reinterpret_cast<const float4*>(qq + 4);
        const unsigned short* vr = bfb + it * BK;
        short8 bf0 = *reinterpret_cast<const short8*>(vr);
        short8 bf1 = *reinterpret_cast<const short8*>(vr + (size_t)1 * 16 * N);
        short8 bf2 = *reinterpret_cast<const short8*>(vr + (size_t)2 * 16 * N);
        short8 bf3 = *reinterpret_cast<const short8*>(vr + (size_t)3 * 16 * N);
        short8 bf4 = *reinterpret_cast<const short8*>(vr + (size_t)4 * 16 * N);
        short8 bf5 = *reinterpret_cast<const short8*>(vr + (size_t)5 * 16 * N);
        short8 bf6 = *reinterpret_cast<const short8*>(vr + (size_t)6 * 16 * N);
        short8 bf7 = *reinterpret_cast<const short8*>(vr + (size_t)7 * 16 * N);

        float w0 = a0.x ? ((x2a.x >= t1a) ? p1a * p2a.x : q1a * q2a.x) : 0.f;
        float w1 = a0.y ? ((x2a.y >= t1a) ? p1a * p2a.y : q1a * q2a.y) : 0.f;
        float w2 = a0.z ? ((x2a.z >= t1a) ? p1a * p2a.z : q1a * q2a.z) : 0.f;
        float w3 = a0.w ? ((x2a.w >= t1a) ? p1a * p2a.w : q1a * q2a.w) : 0.f;
        float w4 = a1.x ? ((x2b.x >= t1a) ? p1a * p2b.x : q1a * q2b.x) : 0.f;
        float w5 = a1.y ? ((x2b.y >= t1a) ? p1a * p2b.y : q1a * q2b.y) : 0.f;
        float w6 = a1.z ? ((x2b.z >= t1a) ? p1a * p2b.z : q1a * q2b.z) : 0.f;
        float w7 = a1.w ? ((x2b.w >= t1a) ? p1a * p2b.w : q1a * q2b.w) : 0.f;
        den0 += ((w0 + w1) + (w2 + w3)) + ((w4 + w5) + (w6 + w7));
        union { short8 s; uint4 u; } af;
        af.u.x = pack_bf2(w0, w1); af.u.y = pack_bf2(w2, w3);
        af.u.z = pack_bf2(w4, w5); af.u.w = pack_bf2(w6, w7);

        acc0[0] = __builtin_amdgcn_mfma_f32_16x16x32_bf16(af.s, bf0, acc0[0], 0, 0, 0);
        acc0[1] = __builtin_amdgcn_mfma_f32_16x16x32_bf16(af.s, bf1, acc0[1], 0, 0, 0);
        acc0[2] = __builtin_amdgcn_mfma_f32_16x16x32_bf16(af.s, bf2, acc0[2], 0, 0, 0);
        acc0[3] = __builtin_amdgcn_mfma_f32_16x16x32_bf16(af.s, bf3, acc0[3], 0, 0, 0);
        acc0[4] = __builtin_amdgcn_mfma_f32_16x16x32_bf16(af.s, bf4, acc0[4], 0, 0, 0);
        acc0[5] = __builtin_amdgcn_mfma_f32_16x16x32_bf16(af.s, bf5, acc0[5], 0, 0, 0);
        acc0[6] = __builtin_amdgcn_mfma_f32_16x16x32_bf16(af.s, bf6, acc0[6], 0, 0, 0);
        acc0[7] = __builtin_amdgcn_mfma_f32_16x16x32_bf16(af.s, bf7, acc0[7], 0, 0, 0);
    };

    // adj ping-pong, depth 2, named registers, wave-uniform conditional prefetch
    int4 aA0, aA1, aB0, aB1;
    {
        const int* p0 = adjb;
        aA0 = *reinterpret_cast<const int4*>(p0);
        aA1 = *reinterpret_cast<const int4*>(p0 + 4);
        const int* p1 = adjb + BK;
        aB0 = *reinterpret_cast<const int4*>(p1);
        aB1 = *reinterpret_cast<const int4*>(p1 + 4);
    }
#pragma unroll 1
    for (int ith = 0; ith < NIT / 2; ith++) {
        int it = ith * 2;
        body(it, aA0, aA1);
        if (it + 2 < NIT) {
            const int* p = adjb + (size_t)(it + 2) * BK;
            aA0 = *reinterpret_cast<const int4*>(p);
            aA1 = *reinterpret_cast<const int4*>(p + 4);
        }
        body(it + 1, aB0, aB1);
        if (it + 3 < NIT) {
            const int* p = adjb + (size_t)(it + 3) * BK;
            aB0 = *reinterpret_cast<const int4*>(p);
            aB1 = *reinterpret_cast<const int4*>(p + 4);
        }
    }

    // ---- epilogue (v3-verified pattern): per-(split,kh) partials, plain global stores ----
    den0 += __shfl_xor(den0, 16);
    den0 += __shfl_xor(den0, 32);
    int pidx = split * 2 + kh;
    float* dp = den_part + (size_t)pidx * BN;
    if (lane < 16) dp[gi0] = den0;   // lanes 0..15 hold rows r0..r0+15's partial den
    float* hp = h_part + (size_t)pidx * BN * F;
    int orow0 = b * N + i0 + rt * 16 + q * 4;  // C/D: row = q*4+reg (within 16-tile), col = nt*16+m
#pragma unroll
    for (int nt = 0; nt < 8; nt++)
#pragma unroll
        for (int r = 0; r < 4; r++)
            hp[(size_t)(orow0 + r) * F + nt * 16 + m] = acc0[nt][r];
}

// ---------------- K4: out = leaky( ((sum_s h_s)/(sum_s den_s)) @ Wo^T )  (v3-verified) ----------------
__global__ __launch_bounds__(256) void k_out(const float* __restrict__ h_part,
                                             const float* __restrict__ den_part,
                                             const float* __restrict__ Wo_w,
                                             float* __restrict__ out) {
    __shared__ float hs[32][F];    // 16 KB
    __shared__ float Ws[F][129];   // 66 KB
    int t = threadIdx.x;
    int row0 = blockIdx.x * 32;    // flat row in [0, BN)
    {
        const float4* src = reinterpret_cast<const float4*>(Wo_w);
#pragma unroll
        for (int u = 0; u < 16; u++) {
            int unit = u * 256 + t;
            int r = unit >> 5, s = unit & 31;
            float4 val = src[unit];
            Ws[r][s * 4 + 0] = val.x; Ws[r][s * 4 + 1] = val.y;
            Ws[r][s * 4 + 2] = val.z; Ws[r][s * 4 + 3] = val.w;
        }
    }
#pragma unroll
    for (int u = 0; u < 4; u++) {
        int unit = u * 256 + t;
        int r = unit >> 5, s = unit & 31;
        size_t off = (size_t)(row0 + r) * F + s * 4;
        float4 h0 = *reinterpret_cast<const float4*>(h_part + off);
        float4 h1 = *reinterpret_cast<const float4*>(h_part + (size_t)BN * F + off);
        float4 h2 = *reinterpret_cast<const float4*>(h_part + (size_t)2 * BN * F + off);
        float4 h3 = *reinterpret_cast<const float4*>(h_part + (size_t)3 * BN * F + off);
        float dsum = den_part[row0 + r] + den_part[BN + row0 + r] +
                     den_part[2 * BN + row0 + r] + den_part[3 * BN + row0 + r];
        float inv = 1.f / dsum;
        hs[r][s * 4 + 0] = (h0.x + h1.x + h2.x + h3.x) * inv;
        hs[r][s * 4 + 1] = (h0.y + h1.y + h2.y + h3.y) * inv;
        hs[r][s * 4 + 2] = (h0.z + h1.z + h2.z + h3.z) * inv;
        hs[r][s * 4 + 3] = (h0.w + h1.w + h2.w + h3.w) * inv;
    }
    __syncthreads();
    int f = t & 127, g = t >> 7;
    float acc[16];
#pragma unroll
    for (int r = 0; r < 16; r++) acc[r] = 0.f;
    for (int kk = 0; kk < F; kk++) {
        float wk = Ws[f][kk];
#pragma unroll
        for (int r = 0; r < 16; r++) acc[r] = fmaf(hs[g * 16 + r][kk], wk, acc[r]);
    }
#pragma unroll
    for (int r = 0; r < 16; r++) out[(size_t)(row0 + g * 16 + r) * F + f] = leaky(acc[r]);
}

extern "C" void kernel_launch(void* const* d_in, const int* in_sizes, int n_in,
                              void* d_out, int out_size, void* d_ws, size_t ws_size,
                              hipStream_t stream) {
    const float* q    = (const float*)d_in[0];
    const float* k    = (const float*)d_in[1];
    const float* v    = (const float*)d_in[2];
    const int*   adj  = (const int*)d_in[3];
    const float* Wq_w = (const float*)d_in[4];
    const float* Wq_b = (const float*)d_in[5];
    const float* Wk_w = (const float*)d_in[6];
    const float* Wk_b = (const float*)d_in[7];
    const float* Wv_w = (const float*)d_in[8];
    const float* Wv_b = (const float*)d_in[9];
    const float* a    = (const float*)d_in[10];
    const float* Wo_w = (const float*)d_in[11];
    float* out = (float*)d_out;
    float* ws = (float*)d_ws;

    unsigned short* vpT = (unsigned short*)ws;        // BN*F bf16 = BN*F/2 floats
    float* h_part   = ws + BN * F / 2;                // 4*BN*F
    float* den_part = h_part + (size_t)4 * BN * F;    // 4*BN
    float* Wh1 = den_part + 4 * BN;
    float* Wh2 = Wh1 + BN;
    float* P1  = Wh2 + BN;
    float* Q1  = P1 + BN;
    float* P2  = Q1 + BN;
    float* Q2  = P2 + BN;
    float* c1  = Q2 + BN;                             // F
    float* c2  = c1 + F;                              // F
    float* d12 = c2 + F;                              // 2
    float* M2  = d12 + 2;                             // B

    k_prep<<<1, 256, 0, stream>>>(Wq_w, Wq_b, Wk_w, Wk_b, a, c1, c2, d12);
    k_wh<<<BN / 8, 256, 0, stream>>>(q, k, c1, c2, d12, Wh1, Wh2);
    k_max2<<<B, 256, 0, stream>>>(Wh2, M2);
    k_tab<<<BN / 256, 256, 0, stream>>>(Wh1, Wh2, M2, P1, Q1, P2, Q2);
    k_vp<<<BN / 32, 256, 0, stream>>>(v, Wv_w, Wv_b, vpT);
    k_attn<<<B * 128 * SPLITS, 256, 0, stream>>>(vpT, adj, Wh1, P1, Q1, P2, Q2, Wh2,
                                                 h_part, den_part);
    k_out<<<BN / 32, 256, 0, stream>>>(h_part, den_part, Wo_w, out);
}